// Round 2
// baseline (373.811 us; speedup 1.0000x reference)
//
#include <hip/hip_runtime.h>

typedef unsigned short u16;
typedef unsigned int uint32;
typedef __bf16 bf16x8 __attribute__((ext_vector_type(8)));
typedef float f32x4 __attribute__((ext_vector_type(4)));

static constexpr int Gg = 64;
static constexpr int Nn = 2048;
static constexpr int Ee = 16384;
static constexpr int GN = Gg * Nn;   // 131072
static constexpr int GE = Gg * Ee;   // 1048576

__device__ __forceinline__ float u2f(u16 u) {
    return __uint_as_float(((uint32)u) << 16);
}
__device__ __forceinline__ u16 f2u(float f) {  // round-to-nearest-even bf16
    uint32 i = __float_as_uint(f);
    uint32 r = (i + 0x7FFFu + ((i >> 16) & 1u)) >> 16;
    return (u16)r;
}

// ---------------- setup kernels ----------------

__global__ void k_zero(int* __restrict__ p) {
    p[blockIdx.x * 256 + threadIdx.x] = 0;
}

__global__ void k_count(const int* __restrict__ ei, int* __restrict__ deg) {
    int e = blockIdx.x * 256 + threadIdx.x;
    atomicAdd(&deg[ei[GE + e]], 1);   // row 1 of edge_index = dst (global ids)
}

// per-graph exclusive scan of degree counts -> absolute CSR offsets; also dis/invdeg
__global__ void k_scan(const int* __restrict__ deg, int* __restrict__ csr_pos,
                       int* __restrict__ cursor, float* __restrict__ dis,
                       float* __restrict__ invdeg) {
    int g = blockIdx.x, t = threadIdx.x;
    __shared__ int s[256];
    int base = g * Nn + t * 8;
    int c[8]; int tot = 0;
    #pragma unroll
    for (int j = 0; j < 8; ++j) { c[j] = deg[base + j]; tot += c[j]; }
    s[t] = tot; __syncthreads();
    for (int off = 1; off < 256; off <<= 1) {
        int v = (t >= off) ? s[t - off] : 0;
        __syncthreads();
        s[t] += v;
        __syncthreads();
    }
    int run = g * Ee + (s[t] - tot);
    #pragma unroll
    for (int j = 0; j < 8; ++j) {
        csr_pos[base + j] = run;
        cursor[base + j] = run;
        float d = 1.0f + (float)c[j];
        dis[base + j] = 1.0f / sqrtf(d);
        invdeg[base + j] = 1.0f / d;
        run += c[j];
    }
}

__global__ void k_scatter(const int* __restrict__ ei, int* __restrict__ cursor,
                          int* __restrict__ csr_src, float* __restrict__ csr_coef,
                          const float* __restrict__ dis) {
    int e = blockIdx.x * 256 + threadIdx.x;
    int s = ei[e];          // src (global id)
    int d = ei[GE + e];     // dst (global id)
    int p = atomicAdd(&cursor[d], 1);
    csr_src[p] = s;
    csr_coef[p] = dis[s] * dis[d];
}

// transpose bottom half of Wm (rows 128..255) -> Wt[c][f] as bf16
__global__ void k_trans(const float* __restrict__ Wm, u16* __restrict__ Wt) {
    int idx = blockIdx.x * 256 + threadIdx.x;   // 16384
    int f = idx >> 7, c = idx & 127;
    Wt[c * 128 + f] = f2u(Wm[(128 + f) * 128 + c]);
}

// per-graph: ce = (sum coef*x[src] + x[center]*invdeg) @ W1 + b1 ; A = ce @ Wm_top + bm
__global__ void k_A(const float* __restrict__ x, const int* __restrict__ center,
                    const int* __restrict__ deg, const int* __restrict__ csr_pos,
                    const int* __restrict__ csr_src, const float* __restrict__ csr_coef,
                    const float* __restrict__ invdeg,
                    const float* __restrict__ W1, const float* __restrict__ b1,
                    const float* __restrict__ Wm, const float* __restrict__ bm,
                    float* __restrict__ A) {
    int g = blockIdx.x, t = threadIdx.x;   // 128 threads
    __shared__ float cepre[128], ce[128];
    int cg = (g << 11) + center[g];
    float v = x[cg * 128 + t] * invdeg[cg];
    int pos = csr_pos[cg], cnt = deg[cg];
    for (int e = pos; e < pos + cnt; ++e)
        v += csr_coef[e] * x[csr_src[e] * 128 + t];
    cepre[t] = v; __syncthreads();
    float a = b1[t];
    #pragma unroll 8
    for (int f = 0; f < 128; ++f) a += cepre[f] * W1[f * 128 + t];
    ce[t] = a; __syncthreads();
    float o = bm[t];
    #pragma unroll 8
    for (int h = 0; h < 128; ++h) o += ce[h] * Wm[h * 128 + t];
    A[g * 128 + t] = o;
}

// ---------------- mask + y GEMM (MFMA) ----------------
// yb[r][c] = bf16( relu( (X @ Wm_bot)[r][c] + A[g][c] ) * x[r][c] )
__global__ __launch_bounds__(256) void k_masky(const float* __restrict__ x,
                                               const u16* __restrict__ Wt,
                                               const float* __restrict__ A,
                                               u16* __restrict__ yb) {
    __shared__ u16 sWt[128 * 128];     // Wt[c][k] bf16, 32 KB
    __shared__ float sA[128];
    __shared__ float sC[4][16 * 128];  // per-wave C tile, 32 KB
    int t = threadIdx.x;
    int rowbase = blockIdx.x * 64;
    int g = rowbase >> 11;             // 64-row block never crosses a graph

    #pragma unroll
    for (int j = 0; j < 8; ++j)
        ((uint4*)sWt)[j * 256 + t] = ((const uint4*)Wt)[j * 256 + t];
    if (t < 128) sA[t] = A[g * 128 + t];
    __syncthreads();

    int w = t >> 6, l = t & 63;
    int row0 = rowbase + w * 16;
    int lm = l & 15, lq = l >> 4;

    f32x4 acc[8] = {};
    #pragma unroll
    for (int ks = 0; ks < 4; ++ks) {
        const float* xp = x + (row0 + lm) * 128 + ks * 32 + lq * 8;
        float4 x0 = *(const float4*)(xp);
        float4 x1 = *(const float4*)(xp + 4);
        union { u16 u[8]; bf16x8 v; } af;
        af.u[0] = f2u(x0.x); af.u[1] = f2u(x0.y); af.u[2] = f2u(x0.z); af.u[3] = f2u(x0.w);
        af.u[4] = f2u(x1.x); af.u[5] = f2u(x1.y); af.u[6] = f2u(x1.z); af.u[7] = f2u(x1.w);
        #pragma unroll
        for (int ct = 0; ct < 8; ++ct) {
            bf16x8 b = *reinterpret_cast<const bf16x8*>(sWt + (ct * 16 + lm) * 128 + ks * 32 + lq * 8);
            acc[ct] = __builtin_amdgcn_mfma_f32_16x16x32_bf16(af.v, b, acc[ct], 0, 0, 0);
        }
    }

    // stage C tile: row=(lq*4+r), col=ct*16+lm
    float* myC = &sC[w][0];
    #pragma unroll
    for (int ct = 0; ct < 8; ++ct)
        #pragma unroll
        for (int r = 0; r < 4; ++r)
            myC[(lq * 4 + r) * 128 + ct * 16 + lm] = acc[ct][r];
    __syncthreads();

    // epilogue: each lane handles one row-quarter (32 cols)
    int lr = l >> 2;
    int cc = (l & 3) * 32;
    int grow = row0 + lr;
    const float* xr = x + grow * 128 + cc;
    u16* yr = yb + grow * 128 + cc;
    #pragma unroll
    for (int j = 0; j < 4; ++j) {
        int c0 = cc + j * 8;
        float4 ca = *(const float4*)(myC + lr * 128 + c0);
        float4 cb = *(const float4*)(myC + lr * 128 + c0 + 4);
        float4 xa = *(const float4*)(xr + j * 8);
        float4 xd = *(const float4*)(xr + j * 8 + 4);
        float m0 = fmaxf(ca.x + sA[c0 + 0], 0.f) * xa.x;
        float m1 = fmaxf(ca.y + sA[c0 + 1], 0.f) * xa.y;
        float m2 = fmaxf(ca.z + sA[c0 + 2], 0.f) * xa.z;
        float m3 = fmaxf(ca.w + sA[c0 + 3], 0.f) * xa.w;
        float m4 = fmaxf(cb.x + sA[c0 + 4], 0.f) * xd.x;
        float m5 = fmaxf(cb.y + sA[c0 + 5], 0.f) * xd.y;
        float m6 = fmaxf(cb.z + sA[c0 + 6], 0.f) * xd.z;
        float m7 = fmaxf(cb.w + sA[c0 + 7], 0.f) * xd.w;
        uint4 o;
        o.x = (uint32)f2u(m0) | ((uint32)f2u(m1) << 16);
        o.y = (uint32)f2u(m2) | ((uint32)f2u(m3) << 16);
        o.z = (uint32)f2u(m4) | ((uint32)f2u(m5) << 16);
        o.w = (uint32)f2u(m6) | ((uint32)f2u(m7) << 16);
        *(uint4*)(yr + j * 8) = o;
    }
}

// ---------------- propagation + graph-mean + output GEMMs ----------------
// block = node i (0..2046); wave w sums graphs [16w,16w+16); then fused matvecs
__global__ __launch_bounds__(256) void k_prop(const float* __restrict__ x, const u16* __restrict__ yb,
                                              const int* __restrict__ deg, const int* __restrict__ csr_pos,
                                              const int* __restrict__ csr_src, const float* __restrict__ csr_coef,
                                              const float* __restrict__ invdeg,
                                              const float* __restrict__ W2, const float* __restrict__ b2,
                                              const float* __restrict__ W3, const float* __restrict__ b3,
                                              float* __restrict__ out) {
    int i = blockIdx.x;
    int t = threadIdx.x, w = t >> 6, l = t & 63;
    int f0 = 2 * l;
    float z0 = 0.f, z1 = 0.f, zx0 = 0.f, zx1 = 0.f;
    for (int g = w * 16; g < w * 16 + 16; ++g) {
        int gid = (g << 11) + i;
        float id = invdeg[gid];
        uint32 yv = *(const uint32*)(yb + gid * 128 + f0);
        float2 xv = *(const float2*)(x + gid * 128 + f0);
        z0 += id * u2f((u16)(yv & 0xffff));  z1 += id * u2f((u16)(yv >> 16));
        zx0 += id * xv.x; zx1 += id * xv.y;
        int pos = csr_pos[gid], cnt = deg[gid];
        for (int e = pos; e < pos + cnt; ++e) {
            int s = csr_src[e];
            float cf = csr_coef[e];
            uint32 yv2 = *(const uint32*)(yb + s * 128 + f0);
            float2 xv2 = *(const float2*)(x + s * 128 + f0);
            z0 += cf * u2f((u16)(yv2 & 0xffff));  z1 += cf * u2f((u16)(yv2 >> 16));
            zx0 += cf * xv2.x; zx1 += cf * xv2.y;
        }
    }
    __shared__ float rz[4][128], rx[4][128], zm[128], zxm[128];
    rz[w][f0] = z0; rz[w][f0 + 1] = z1;
    rx[w][f0] = zx0; rx[w][f0 + 1] = zx1;
    __syncthreads();
    if (t < 128) {
        zm[t]  = (rz[0][t] + rz[1][t] + rz[2][t] + rz[3][t]) * (1.0f / 64.0f);
        zxm[t] = (rx[0][t] + rx[1][t] + rx[2][t] + rx[3][t]) * (1.0f / 64.0f);
    }
    __syncthreads();
    int c = t & 127;
    if (t < 128) {
        float acc = b2[c];
        #pragma unroll 8
        for (int f = 0; f < 128; ++f) acc += zm[f] * W2[f * 128 + c];
        out[i * 128 + c] = acc;
    } else {
        float acc = b3[c];
        #pragma unroll 8
        for (int f = 0; f < 128; ++f) acc += (zxm[f] - zm[f]) * W3[f * 128 + c];
        out[2047 * 128 + i * 128 + c] = acc;
    }
}

// ---------------- launch ----------------

extern "C" void kernel_launch(void* const* d_in, const int* in_sizes, int n_in,
                              void* d_out, int out_size, void* d_ws, size_t ws_size,
                              hipStream_t stream) {
    const float* x    = (const float*)d_in[0];
    const int* ei     = (const int*)d_in[1];
    // d_in[2] = batch (unused)
    const int* center = (const int*)d_in[3];
    const float* W1 = (const float*)d_in[4];
    const float* b1 = (const float*)d_in[5];
    const float* W2 = (const float*)d_in[6];
    const float* b2 = (const float*)d_in[7];
    const float* W3 = (const float*)d_in[8];
    const float* b3 = (const float*)d_in[9];
    const float* Wm = (const float*)d_in[10];
    const float* bm = (const float*)d_in[11];
    float* out = (float*)d_out;

    char* ws = (char*)d_ws;
    int*   degc     = (int*)(ws + 0);          // 512 KB
    int*   csr_pos  = (int*)(ws + 524288);     // 512 KB
    int*   cursor   = (int*)(ws + 1048576);    // 512 KB
    float* dis      = (float*)(ws + 1572864);  // 512 KB
    float* invdeg   = (float*)(ws + 2097152);  // 512 KB
    float* A        = (float*)(ws + 2621440);  // 32 KB
    u16*   Wt       = (u16*)(ws + 2654208);    // 32 KB
    int*   csr_src  = (int*)(ws + 2686976);    // 4 MB
    float* csr_coef = (float*)(ws + 6881280);  // 4 MB
    u16*   yb       = (u16*)(ws + 11075584);   // 32 MB (131072*128 bf16)

    k_zero<<<dim3(GN / 256), dim3(256), 0, stream>>>(degc);
    k_count<<<dim3(GE / 256), dim3(256), 0, stream>>>(ei, degc);
    k_scan<<<dim3(Gg), dim3(256), 0, stream>>>(degc, csr_pos, cursor, dis, invdeg);
    k_scatter<<<dim3(GE / 256), dim3(256), 0, stream>>>(ei, cursor, csr_src, csr_coef, dis);
    k_trans<<<dim3(64), dim3(256), 0, stream>>>(Wm, Wt);
    k_A<<<dim3(Gg), dim3(128), 0, stream>>>(x, center, degc, csr_pos, csr_src, csr_coef,
                                            invdeg, W1, b1, Wm, bm, A);
    k_masky<<<dim3(GN / 64), dim3(256), 0, stream>>>(x, Wt, A, yb);
    k_prop<<<dim3(Nn - 1), dim3(256), 0, stream>>>(x, yb, degc, csr_pos, csr_src, csr_coef,
                                                   invdeg, W2, b2, W3, b3, out);
}